// Round 7
// baseline (1010.465 us; speedup 1.0000x reference)
//
#include <hip/hip_runtime.h>
#include <math.h>

#define B_TOK 4096
#define D_DIM 768
#define E_NUM 8
#define L_LAT 3072
#define K_TOP 32

// output buffer offsets (all float32, concatenated in reference return order)
#define O_SAE  0
#define O_ACTS (B_TOK*D_DIM)            // 3145728
#define O_IDX  (O_ACTS + B_TOK*K_TOP)   // 3276800
#define O_FVU  (O_IDX + B_TOK*K_TOP)    // 3407872
#define O_AUX  (O_FVU + 1)              // 3407873
#define O_MTK  (O_AUX + 1)              // 3407874
#define O_EID  (O_MTK + 1)              // 3407875
#define O_LBL  (O_EID + B_TOK)          // 3411971

struct Ws {
  double S[E_NUM][D_DIM];
  double S2[E_NUM][D_DIM];
  double var_[E_NUM];
  double l2[E_NUM];
  float  sel[B_TOK];
  int    eid[B_TOK];
  int    perm[B_TOK];
  int    counts[E_NUM];
  int    off[E_NUM + 1];
  int    pad[32];
};

__global__ void init_k(Ws* ws, float* out) {
  int tid = threadIdx.x;
  if (tid < E_NUM) { ws->counts[tid] = 0; ws->l2[tid] = 0.0; }
  if (tid == 0) { out[O_AUX] = 0.0f; out[O_MTK] = 0.0f; }
}

// one wave per token, f64 router (expert_ids exact across R1-R6)
__global__ void router_k(const float* __restrict__ x, const float* __restrict__ rw,
                         const float* __restrict__ rb, Ws* ws, float* out) {
  int t = blockIdx.x;
  int lane = threadIdx.x;
  double acc[E_NUM];
#pragma unroll
  for (int e = 0; e < E_NUM; ++e) acc[e] = 0.0;
  const float* xr = x + (size_t)t * D_DIM;
#pragma unroll
  for (int j = 0; j < D_DIM / 64; ++j) {
    int d = lane + 64 * j;
    float xv = xr[d];
#pragma unroll
    for (int e = 0; e < E_NUM; ++e) acc[e] += (double)xv * (double)rw[e * D_DIM + d];
  }
#pragma unroll
  for (int e = 0; e < E_NUM; ++e) {
#pragma unroll
    for (int o = 32; o; o >>= 1) acc[e] += __shfl_down(acc[e], o);
  }
  if (lane == 0) {
    double lg[E_NUM];
    int be = 0; double bm = -1e300;
#pragma unroll
    for (int e = 0; e < E_NUM; ++e) {
      lg[e] = acc[e] + (double)rb[e];
      if (lg[e] > bm) { bm = lg[e]; be = e; }
    }
    double s = 0.0;
#pragma unroll
    for (int e = 0; e < E_NUM; ++e) s += exp(lg[e] - bm);
    ws->sel[t] = (float)(1.0 / s);
    ws->eid[t] = be;
    atomicAdd(&ws->counts[be], 1);
    out[O_EID + t] = (float)be;
  }
}

__global__ void scan_k(Ws* ws, float* out) {
  if (threadIdx.x == 0) {
    int o = 0; double loss = 0.0;
    for (int e = 0; e < E_NUM; ++e) {
      ws->off[e] = o;
      int c = ws->counts[e];
      o += c;
      double f = (double)c / (double)B_TOK - 1.0 / (double)E_NUM;
      loss += f * f;
    }
    ws->off[E_NUM] = o;
    out[O_LBL] = (float)loss;
  }
}

// deterministic stable compaction: one block per expert
__global__ void group_k(Ws* ws) {
  int e = blockIdx.x, tid = threadIdx.x;
  __shared__ int cnt[256];
  const int CH = B_TOK / 256;
  int i0 = tid * CH;
  int c = 0;
#pragma unroll
  for (int i = 0; i < CH; ++i) c += (ws->eid[i0 + i] == e) ? 1 : 0;
  cnt[tid] = c;
  __syncthreads();
  int excl = 0;
  for (int i = 0; i < tid; ++i) excl += cnt[i];
  int base = ws->off[e] + excl;
  for (int i = 0; i < CH; ++i) {
    int t = i0 + i;
    if (ws->eid[t] == e) ws->perm[base++] = t;
  }
}

__global__ void stats_k(const float* __restrict__ x, Ws* ws) {
  int e = blockIdx.x / 3, chunk = blockIdx.x % 3;
  int d = chunk * 256 + threadIdx.x;
  int s0 = ws->off[e], s1 = ws->off[e + 1];
  double S = 0.0, S2 = 0.0;
  for (int i = s0; i < s1; ++i) {
    float xv = x[(size_t)ws->perm[i] * D_DIM + d];
    S += (double)xv;
    S2 += (double)xv * (double)xv;
  }
  ws->S[e][d] = S;
  ws->S2[e][d] = S2;
}

__global__ void var_k(Ws* ws) {
  int e = blockIdx.x, tid = threadIdx.x;
  int n = ws->counts[e];
  double nd = (double)((n > 0) ? n : 1);
  double acc = 0.0;
  for (int d = tid; d < D_DIM; d += 256) {
    double S = ws->S[e][d], S2 = ws->S2[e][d];
    double m = S / nd;
    acc += S2 - 2.0 * m * S + (double)n * m * m;
  }
  __shared__ double red[256];
  red[tid] = acc;
  __syncthreads();
  for (int s = 128; s; s >>= 1) {
    if (tid < s) red[tid] += red[tid + s];
    __syncthreads();
  }
  if (tid == 0) ws->var_[e] = red[0];
}

// -------- f32 GEMM replicating BLIS (AOCL) sgemm accumulation --------------
// BLIS zen sgemm KC=512, greedy panels, plain remainder: K=768 -> 512+256.
// Each panel: strictly sequential ascending-k single-accumulator fma chain
// from zero (one acc per C element -- register budget forces this in all
// packed-BLAS microkernels). Combined (S1+S2), + b_enc, relu.
// tile: 64 tokens x 64 latents, 256 threads, 4x4 microtile.
#define KTILE(ACC, K0) do {                                                    \
  __syncthreads();                                                             \
  _Pragma("unroll")                                                            \
  for (int p = 0; p < 8; ++p) {                                                \
    int m = p * 256 + tid; int r = m >> 5, kk = m & 31;                        \
    xs[r][kk]  = x[(size_t)tokrow[r] * D_DIM + (K0) + kk]                      \
                 - bdec[e * D_DIM + (K0) + kk];                                \
    wsh[r][kk] = We[wb + (size_t)(bl + r) * D_DIM + (K0) + kk];                \
  }                                                                            \
  __syncthreads();                                                             \
  _Pragma("unroll")                                                            \
  for (int kk = 0; kk < 32; ++kk) {                                            \
    float a0 = xs[ty4 + 0][kk], a1 = xs[ty4 + 1][kk];                          \
    float a2 = xs[ty4 + 2][kk], a3 = xs[ty4 + 3][kk];                          \
    float b0 = wsh[tx4 + 0][kk], b1 = wsh[tx4 + 1][kk];                        \
    float b2 = wsh[tx4 + 2][kk], b3 = wsh[tx4 + 3][kk];                        \
    ACC[0][0] = fmaf(a0, b0, ACC[0][0]); ACC[0][1] = fmaf(a0, b1, ACC[0][1]);  \
    ACC[0][2] = fmaf(a0, b2, ACC[0][2]); ACC[0][3] = fmaf(a0, b3, ACC[0][3]);  \
    ACC[1][0] = fmaf(a1, b0, ACC[1][0]); ACC[1][1] = fmaf(a1, b1, ACC[1][1]);  \
    ACC[1][2] = fmaf(a1, b2, ACC[1][2]); ACC[1][3] = fmaf(a1, b3, ACC[1][3]);  \
    ACC[2][0] = fmaf(a2, b0, ACC[2][0]); ACC[2][1] = fmaf(a2, b1, ACC[2][1]);  \
    ACC[2][2] = fmaf(a2, b2, ACC[2][2]); ACC[2][3] = fmaf(a2, b3, ACC[2][3]);  \
    ACC[3][0] = fmaf(a3, b0, ACC[3][0]); ACC[3][1] = fmaf(a3, b1, ACC[3][1]);  \
    ACC[3][2] = fmaf(a3, b2, ACC[3][2]); ACC[3][3] = fmaf(a3, b3, ACC[3][3]);  \
  }                                                                            \
} while (0)

__launch_bounds__(256)
__global__ void gemm_k(const float* __restrict__ x, const float* __restrict__ We,
                       const float* __restrict__ benc, const float* __restrict__ bdec,
                       Ws* ws, float* __restrict__ pre) {
  int e = blockIdx.z;
  int n0 = ws->off[e], n1 = ws->off[e + 1];
  int ne = n1 - n0;
  int bt = blockIdx.y * 64;
  if (bt >= ne) return;
  int bl = blockIdx.x * 64;

  __shared__ float xs[64][33];
  __shared__ float wsh[64][33];
  __shared__ int tokrow[64];

  int tid = threadIdx.x;
  if (tid < 64) {
    int srow = bt + tid;
    tokrow[tid] = ws->perm[n0 + (srow < ne ? srow : 0)];
  }

  int tx = tid & 15, ty = tid >> 4;
  int tx4 = tx * 4, ty4 = ty * 4;
  size_t wb = (size_t)e * L_LAT * D_DIM;

  float acc1[4][4] = {{0.f}}, acc2[4][4] = {{0.f}};

  for (int k0 = 0;   k0 < 512; k0 += 32) KTILE(acc1, k0);  // panel 1: [0,512)
  for (int k0 = 512; k0 < 768; k0 += 32) KTILE(acc2, k0);  // panel 2: [512,768)

#pragma unroll
  for (int i = 0; i < 4; ++i) {
    int srow = bt + ty4 + i;
    if (srow < ne) {
      float4 v;
      float* vp = &v.x;
#pragma unroll
      for (int j = 0; j < 4; ++j) {
        int l = bl + tx4 + j;
        float r = (acc1[i][j] + acc2[i][j]) + benc[e * L_LAT + l];
        vp[j] = fmaxf(r, 0.0f);
      }
      *(float4*)&pre[(size_t)(n0 + srow) * L_LAT + bl + tx4] = v;
    }
  }
}

// per-wave top-32 with exact jax.lax.top_k tie rule (value desc, index asc)
__launch_bounds__(256)
__global__ void topk_k(const float* __restrict__ pre, Ws* ws, float* out) {
  __shared__ float buf[4][L_LAT];
  int tid = threadIdx.x, wave = tid >> 6, lane = tid & 63;
  int s = blockIdx.x * 4 + wave;
  int t = ws->perm[s];
  const float* src = pre + (size_t)s * L_LAT;
#pragma unroll
  for (int j = 0; j < L_LAT / 64; ++j) buf[wave][lane + 64 * j] = src[lane + 64 * j];

  unsigned long long bk = 0ULL;
#pragma unroll
  for (int j = 0; j < L_LAT / 64; ++j) {
    int l = lane + 64 * j;
    float v = buf[wave][l];
    if (v >= 0.0f) {
      unsigned long long key = ((unsigned long long)__float_as_uint(v) << 32)
                             | (unsigned long long)(0xFFFFFFFFu - (unsigned)l);
      if (key > bk) bk = key;
    }
  }
  for (int k = 0; k < K_TOP; ++k) {
    unsigned long long m = bk;
#pragma unroll
    for (int o = 32; o; o >>= 1) {
      unsigned long long o2 = __shfl_down(m, o);
      if (o2 > m) m = o2;
    }
    m = __shfl(m, 0);
    int l = (int)(0xFFFFFFFFu - (unsigned)(m & 0xFFFFFFFFull));
    float v = __uint_as_float((unsigned)(m >> 32));
    if (lane == 0) {
      out[O_ACTS + (size_t)t * K_TOP + k] = v;
      out[O_IDX + (size_t)t * K_TOP + k] = (float)l;
    }
    if ((l & 63) == lane) {
      buf[wave][l] = -1.0f;
      bk = 0ULL;
#pragma unroll
      for (int j = 0; j < L_LAT / 64; ++j) {
        int ll = lane + 64 * j;
        float vv = buf[wave][ll];
        if (vv >= 0.0f) {
          unsigned long long key = ((unsigned long long)__float_as_uint(vv) << 32)
                                 | (unsigned long long)(0xFFFFFFFFu - (unsigned)ll);
          if (key > bk) bk = key;
        }
      }
    }
  }
}

// decode + sae_out + per-expert L2
__global__ void decode_k(const float* __restrict__ x, const float* __restrict__ Wdec,
                         const float* __restrict__ bdec, Ws* ws, float* out) {
  int t = blockIdx.x, tid = threadIdx.x;
  int e = ws->eid[t];
  float sp = ws->sel[t];
  __shared__ float sa[K_TOP];
  __shared__ int si[K_TOP];
  if (tid < K_TOP) {
    sa[tid] = out[O_ACTS + (size_t)t * K_TOP + tid];
    si[tid] = (int)out[O_IDX + (size_t)t * K_TOP + tid];
  }
  __syncthreads();
  float r0 = 0.f, r1 = 0.f, r2 = 0.f;
  const float* wdb = Wdec + (size_t)e * L_LAT * D_DIM;
#pragma unroll 4
  for (int k = 0; k < K_TOP; ++k) {
    const float* wr = wdb + (size_t)si[k] * D_DIM;
    float a = sa[k];
    r0 = fmaf(a, wr[tid], r0);
    r1 = fmaf(a, wr[tid + 256], r1);
    r2 = fmaf(a, wr[tid + 512], r2);
  }
  const float* bd = bdec + e * D_DIM;
  float rec0 = r0 + bd[tid];
  float rec1 = r1 + bd[tid + 256];
  float rec2 = r2 + bd[tid + 512];
  const float* xr = x + (size_t)t * D_DIM;
  float* so = out + O_SAE + (size_t)t * D_DIM;
  so[tid] = rec0 * sp;
  so[tid + 256] = rec1 * sp;
  so[tid + 512] = rec2 * sp;
  double d0 = (double)(xr[tid] - rec0);
  double d1 = (double)(xr[tid + 256] - rec1);
  double d2 = (double)(xr[tid + 512] - rec2);
  double l2p = d0 * d0 + d1 * d1 + d2 * d2;
  __shared__ double red[256];
  red[tid] = l2p;
  __syncthreads();
  for (int s = 128; s; s >>= 1) {
    if (tid < s) red[tid] += red[tid + s];
    __syncthreads();
  }
  if (tid == 0) atomicAdd(&ws->l2[e], red[0]);
}

__global__ void final_k(Ws* ws, float* out) {
  if (threadIdx.x == 0) {
    double tot = 0.0;
    for (int e = 0; e < E_NUM; ++e) {
      int n = ws->counts[e];
      double v = ws->var_[e];
      if (n > 0 && v > 0.0) tot += ws->l2[e] / fmax(v, 1e-12) * (double)n;
    }
    out[O_FVU] = (float)(tot / (double)B_TOK);
  }
}

extern "C" void kernel_launch(void* const* d_in, const int* in_sizes, int n_in,
                              void* d_out, int out_size, void* d_ws, size_t ws_size,
                              hipStream_t stream) {
  const float* x  = (const float*)d_in[0];
  const float* rw = (const float*)d_in[1];
  const float* rb = (const float*)d_in[2];
  const float* We = (const float*)d_in[3];
  const float* be = (const float*)d_in[4];
  const float* Wd = (const float*)d_in[5];
  const float* bd = (const float*)d_in[6];
  float* out = (float*)d_out;
  Ws* ws = (Ws*)d_ws;
  float* pre = (float*)((char*)d_ws + ((sizeof(Ws) + 255) & ~(size_t)255));

  hipLaunchKernelGGL(init_k,   dim3(1),           dim3(64),  0, stream, ws, out);
  hipLaunchKernelGGL(router_k, dim3(B_TOK),       dim3(64),  0, stream, x, rw, rb, ws, out);
  hipLaunchKernelGGL(scan_k,   dim3(1),           dim3(64),  0, stream, ws, out);
  hipLaunchKernelGGL(group_k,  dim3(E_NUM),       dim3(256), 0, stream, ws);
  hipLaunchKernelGGL(stats_k,  dim3(24),          dim3(256), 0, stream, x, ws);
  hipLaunchKernelGGL(gemm_k,   dim3(48, 64, 8),   dim3(256), 0, stream, x, We, be, bd, ws, pre);
  hipLaunchKernelGGL(var_k,    dim3(E_NUM),       dim3(256), 0, stream, ws);
  hipLaunchKernelGGL(topk_k,   dim3(B_TOK / 4),   dim3(256), 0, stream, pre, ws, out);
  hipLaunchKernelGGL(decode_k, dim3(B_TOK),       dim3(256), 0, stream, x, Wd, bd, ws, out);
  hipLaunchKernelGGL(final_k,  dim3(1),           dim3(64),  0, stream, ws, out);
}

// Round 8
// 837.503 us; speedup vs baseline: 1.2065x; 1.2065x over previous
//
#include <hip/hip_runtime.h>
#include <math.h>

#define B_TOK 4096
#define D_DIM 768
#define E_NUM 8
#define L_LAT 3072
#define K_TOP 32

// output buffer offsets (all float32, concatenated in reference return order)
#define O_SAE  0
#define O_ACTS (B_TOK*D_DIM)            // 3145728
#define O_IDX  (O_ACTS + B_TOK*K_TOP)   // 3276800
#define O_FVU  (O_IDX + B_TOK*K_TOP)    // 3407872
#define O_AUX  (O_FVU + 1)              // 3407873
#define O_MTK  (O_AUX + 1)              // 3407874
#define O_EID  (O_MTK + 1)              // 3407875
#define O_LBL  (O_EID + B_TOK)          // 3411971

struct Ws {
  double S[E_NUM][D_DIM];
  double S2[E_NUM][D_DIM];
  double var_[E_NUM];
  double l2[E_NUM];
  float  sel[B_TOK];
  int    eid[B_TOK];
  int    perm[B_TOK];
  int    counts[E_NUM];
  int    off[E_NUM + 1];
  int    pad[32];
};

__global__ void init_k(Ws* ws, float* out) {
  int tid = threadIdx.x;
  if (tid < E_NUM) { ws->counts[tid] = 0; ws->l2[tid] = 0.0; }
  if (tid == 0) { out[O_AUX] = 0.0f; out[O_MTK] = 0.0f; }
}

// one wave per token, f64 router (expert_ids exact across R1-R7)
__global__ void router_k(const float* __restrict__ x, const float* __restrict__ rw,
                         const float* __restrict__ rb, Ws* ws, float* out) {
  int t = blockIdx.x;
  int lane = threadIdx.x;
  double acc[E_NUM];
#pragma unroll
  for (int e = 0; e < E_NUM; ++e) acc[e] = 0.0;
  const float* xr = x + (size_t)t * D_DIM;
#pragma unroll
  for (int j = 0; j < D_DIM / 64; ++j) {
    int d = lane + 64 * j;
    float xv = xr[d];
#pragma unroll
    for (int e = 0; e < E_NUM; ++e) acc[e] += (double)xv * (double)rw[e * D_DIM + d];
  }
#pragma unroll
  for (int e = 0; e < E_NUM; ++e) {
#pragma unroll
    for (int o = 32; o; o >>= 1) acc[e] += __shfl_down(acc[e], o);
  }
  if (lane == 0) {
    double lg[E_NUM];
    int be = 0; double bm = -1e300;
#pragma unroll
    for (int e = 0; e < E_NUM; ++e) {
      lg[e] = acc[e] + (double)rb[e];
      if (lg[e] > bm) { bm = lg[e]; be = e; }
    }
    double s = 0.0;
#pragma unroll
    for (int e = 0; e < E_NUM; ++e) s += exp(lg[e] - bm);
    ws->sel[t] = (float)(1.0 / s);
    ws->eid[t] = be;
    atomicAdd(&ws->counts[be], 1);
    out[O_EID + t] = (float)be;
  }
}

__global__ void scan_k(Ws* ws, float* out) {
  if (threadIdx.x == 0) {
    int o = 0; double loss = 0.0;
    for (int e = 0; e < E_NUM; ++e) {
      ws->off[e] = o;
      int c = ws->counts[e];
      o += c;
      double f = (double)c / (double)B_TOK - 1.0 / (double)E_NUM;
      loss += f * f;
    }
    ws->off[E_NUM] = o;
    out[O_LBL] = (float)loss;
  }
}

// deterministic stable compaction: one block per expert
__global__ void group_k(Ws* ws) {
  int e = blockIdx.x, tid = threadIdx.x;
  __shared__ int cnt[256];
  const int CH = B_TOK / 256;
  int i0 = tid * CH;
  int c = 0;
#pragma unroll
  for (int i = 0; i < CH; ++i) c += (ws->eid[i0 + i] == e) ? 1 : 0;
  cnt[tid] = c;
  __syncthreads();
  int excl = 0;
  for (int i = 0; i < tid; ++i) excl += cnt[i];
  int base = ws->off[e] + excl;
  for (int i = 0; i < CH; ++i) {
    int t = i0 + i;
    if (ws->eid[t] == e) ws->perm[base++] = t;
  }
}

__global__ void stats_k(const float* __restrict__ x, Ws* ws) {
  int e = blockIdx.x / 3, chunk = blockIdx.x % 3;
  int d = chunk * 256 + threadIdx.x;
  int s0 = ws->off[e], s1 = ws->off[e + 1];
  double S = 0.0, S2 = 0.0;
  for (int i = s0; i < s1; ++i) {
    float xv = x[(size_t)ws->perm[i] * D_DIM + d];
    S += (double)xv;
    S2 += (double)xv * (double)xv;
  }
  ws->S[e][d] = S;
  ws->S2[e][d] = S2;
}

__global__ void var_k(Ws* ws) {
  int e = blockIdx.x, tid = threadIdx.x;
  int n = ws->counts[e];
  double nd = (double)((n > 0) ? n : 1);
  double acc = 0.0;
  for (int d = tid; d < D_DIM; d += 256) {
    double S = ws->S[e][d], S2 = ws->S2[e][d];
    double m = S / nd;
    acc += S2 - 2.0 * m * S + (double)n * m * m;
  }
  __shared__ double red[256];
  red[tid] = acc;
  __syncthreads();
  for (int s = 128; s; s >>= 1) {
    if (tid < s) red[tid] += red[tid + s];
    __syncthreads();
  }
  if (tid == 0) ws->var_[e] = red[0];
}

// -------- f32 GEMM, BLIS (AOCL) accumulation: panels 512+256, (S1+S2) ------
// Per C element the FP op sequence is FROZEN (passed R7): sequential
// ascending-k fma chain per panel, then (acc1+acc2)+b_enc, relu.
// Retiled for LDS throughput: 128x128 block tile, 256 threads, 8x8 microtile
// with STRIDED ownership (rows ty+16i, cols tx+16j) so ds_read_b128 at LDS
// stride 36 floats is conflict-free (a: 4 distinct banks; b: 8 banks x 2-way).
#define KTILE(ACC, K0) do {                                                    \
  __syncthreads();                                                             \
  _Pragma("unroll")                                                            \
  for (int p = 0; p < 4; ++p) {                                                \
    int idx = p * 256 + tid;                                                   \
    int r = idx >> 3, c4 = (idx & 7) * 4;                                      \
    float4 xv = *(const float4*)(x + (size_t)tokrow[r] * D_DIM + (K0) + c4);   \
    float4 bv = *(const float4*)(bdec + e * D_DIM + (K0) + c4);                \
    float4 xm = make_float4(xv.x - bv.x, xv.y - bv.y, xv.z - bv.z, xv.w - bv.w);\
    *(float4*)&xs[r][c4] = xm;                                                 \
    *(float4*)&wsh[r][c4] =                                                    \
        *(const float4*)(We + wb + (size_t)(bl + r) * D_DIM + (K0) + c4);      \
  }                                                                            \
  __syncthreads();                                                             \
  _Pragma("unroll")                                                            \
  for (int q = 0; q < 8; ++q) {                                                \
    float4 a[8], b[8];                                                         \
    _Pragma("unroll")                                                          \
    for (int i = 0; i < 8; ++i) a[i] = *(const float4*)&xs[ty + 16 * i][q * 4];\
    _Pragma("unroll")                                                          \
    for (int j = 0; j < 8; ++j) b[j] = *(const float4*)&wsh[tx + 16 * j][q * 4];\
    _Pragma("unroll")                                                          \
    for (int i = 0; i < 8; ++i) {                                              \
      _Pragma("unroll")                                                        \
      for (int j = 0; j < 8; ++j) {                                            \
        ACC[i][j] = fmaf(a[i].x, b[j].x, ACC[i][j]);                           \
        ACC[i][j] = fmaf(a[i].y, b[j].y, ACC[i][j]);                           \
        ACC[i][j] = fmaf(a[i].z, b[j].z, ACC[i][j]);                           \
        ACC[i][j] = fmaf(a[i].w, b[j].w, ACC[i][j]);                           \
      }                                                                        \
    }                                                                          \
  }                                                                            \
} while (0)

__launch_bounds__(256, 2)
__global__ void gemm_k(const float* __restrict__ x, const float* __restrict__ We,
                       const float* __restrict__ benc, const float* __restrict__ bdec,
                       Ws* ws, float* __restrict__ pre) {
  int e = blockIdx.z;
  int n0 = ws->off[e], n1 = ws->off[e + 1];
  int ne = n1 - n0;
  int bt = blockIdx.y * 128;
  if (bt >= ne) return;
  int bl = blockIdx.x * 128;

  __shared__ float xs[128][36];
  __shared__ float wsh[128][36];
  __shared__ int tokrow[128];

  int tid = threadIdx.x;
  if (tid < 128) {
    int srow = bt + tid;
    tokrow[tid] = ws->perm[n0 + (srow < ne ? srow : 0)];
  }

  int tx = tid & 15, ty = tid >> 4;
  size_t wb = (size_t)e * L_LAT * D_DIM;

  float acc1[8][8] = {{0.f}}, acc2[8][8] = {{0.f}};

  for (int k0 = 0;   k0 < 512; k0 += 32) KTILE(acc1, k0);  // panel 1: [0,512)
  for (int k0 = 512; k0 < 768; k0 += 32) KTILE(acc2, k0);  // panel 2: [512,768)

#pragma unroll
  for (int i = 0; i < 8; ++i) {
    int srow = bt + ty + 16 * i;
    if (srow < ne) {
      float* pr = &pre[(size_t)(n0 + srow) * L_LAT + bl];
#pragma unroll
      for (int j = 0; j < 8; ++j) {
        int lc = tx + 16 * j;
        float r = (acc1[i][j] + acc2[i][j]) + benc[e * L_LAT + bl + lc];
        pr[lc] = fmaxf(r, 0.0f);
      }
    }
  }
}

// per-wave top-32 with exact jax.lax.top_k tie rule (value desc, index asc)
__launch_bounds__(256)
__global__ void topk_k(const float* __restrict__ pre, Ws* ws, float* out) {
  __shared__ float buf[4][L_LAT];
  int tid = threadIdx.x, wave = tid >> 6, lane = tid & 63;
  int s = blockIdx.x * 4 + wave;
  int t = ws->perm[s];
  const float* src = pre + (size_t)s * L_LAT;
#pragma unroll
  for (int j = 0; j < L_LAT / 64; ++j) buf[wave][lane + 64 * j] = src[lane + 64 * j];

  unsigned long long bk = 0ULL;
#pragma unroll
  for (int j = 0; j < L_LAT / 64; ++j) {
    int l = lane + 64 * j;
    float v = buf[wave][l];
    if (v >= 0.0f) {
      unsigned long long key = ((unsigned long long)__float_as_uint(v) << 32)
                             | (unsigned long long)(0xFFFFFFFFu - (unsigned)l);
      if (key > bk) bk = key;
    }
  }
  for (int k = 0; k < K_TOP; ++k) {
    unsigned long long m = bk;
#pragma unroll
    for (int o = 32; o; o >>= 1) {
      unsigned long long o2 = __shfl_down(m, o);
      if (o2 > m) m = o2;
    }
    m = __shfl(m, 0);
    int l = (int)(0xFFFFFFFFu - (unsigned)(m & 0xFFFFFFFFull));
    float v = __uint_as_float((unsigned)(m >> 32));
    if (lane == 0) {
      out[O_ACTS + (size_t)t * K_TOP + k] = v;
      out[O_IDX + (size_t)t * K_TOP + k] = (float)l;
    }
    if ((l & 63) == lane) {
      buf[wave][l] = -1.0f;
      bk = 0ULL;
#pragma unroll
      for (int j = 0; j < L_LAT / 64; ++j) {
        int ll = lane + 64 * j;
        float vv = buf[wave][ll];
        if (vv >= 0.0f) {
          unsigned long long key = ((unsigned long long)__float_as_uint(vv) << 32)
                                 | (unsigned long long)(0xFFFFFFFFu - (unsigned)ll);
          if (key > bk) bk = key;
        }
      }
    }
  }
}

// decode + sae_out + per-expert L2 : 192 threads/token, float4 Wdec gathers
__launch_bounds__(192)
__global__ void decode_k(const float* __restrict__ x, const float* __restrict__ Wdec,
                         const float* __restrict__ bdec, Ws* ws, float* out) {
  int t = blockIdx.x, tid = threadIdx.x;
  int e = ws->eid[t];
  float sp = ws->sel[t];
  __shared__ float sa[K_TOP];
  __shared__ int si[K_TOP];
  if (tid < K_TOP) {
    sa[tid] = out[O_ACTS + (size_t)t * K_TOP + tid];
    si[tid] = (int)out[O_IDX + (size_t)t * K_TOP + tid];
  }
  __syncthreads();
  int d4 = tid * 4;
  float4 r = make_float4(0.f, 0.f, 0.f, 0.f);
  const float* wdb = Wdec + (size_t)e * L_LAT * D_DIM;
#pragma unroll 4
  for (int k = 0; k < K_TOP; ++k) {
    float4 w = *(const float4*)(wdb + (size_t)si[k] * D_DIM + d4);
    float a = sa[k];
    r.x = fmaf(a, w.x, r.x);
    r.y = fmaf(a, w.y, r.y);
    r.z = fmaf(a, w.z, r.z);
    r.w = fmaf(a, w.w, r.w);
  }
  float4 bd = *(const float4*)(bdec + e * D_DIM + d4);
  float4 rec = make_float4(r.x + bd.x, r.y + bd.y, r.z + bd.z, r.w + bd.w);
  float4 xr = *(const float4*)(x + (size_t)t * D_DIM + d4);
  float4 so = make_float4(rec.x * sp, rec.y * sp, rec.z * sp, rec.w * sp);
  *(float4*)&out[O_SAE + (size_t)t * D_DIM + d4] = so;
  double d0 = (double)(xr.x - rec.x);
  double d1 = (double)(xr.y - rec.y);
  double d2 = (double)(xr.z - rec.z);
  double d3 = (double)(xr.w - rec.w);
  double l2p = d0 * d0 + d1 * d1 + d2 * d2 + d3 * d3;
  __shared__ double red[192];
  red[tid] = l2p;
  __syncthreads();
  for (int s = 96; s >= 3; s >>= 1) {
    if (tid < s) red[tid] += red[tid + s];
    __syncthreads();
  }
  if (tid == 0) atomicAdd(&ws->l2[e], red[0] + red[1] + red[2]);
}

__global__ void final_k(Ws* ws, float* out) {
  if (threadIdx.x == 0) {
    double tot = 0.0;
    for (int e = 0; e < E_NUM; ++e) {
      int n = ws->counts[e];
      double v = ws->var_[e];
      if (n > 0 && v > 0.0) tot += ws->l2[e] / fmax(v, 1e-12) * (double)n;
    }
    out[O_FVU] = (float)(tot / (double)B_TOK);
  }
}

extern "C" void kernel_launch(void* const* d_in, const int* in_sizes, int n_in,
                              void* d_out, int out_size, void* d_ws, size_t ws_size,
                              hipStream_t stream) {
  const float* x  = (const float*)d_in[0];
  const float* rw = (const float*)d_in[1];
  const float* rb = (const float*)d_in[2];
  const float* We = (const float*)d_in[3];
  const float* be = (const float*)d_in[4];
  const float* Wd = (const float*)d_in[5];
  const float* bd = (const float*)d_in[6];
  float* out = (float*)d_out;
  Ws* ws = (Ws*)d_ws;
  float* pre = (float*)((char*)d_ws + ((sizeof(Ws) + 255) & ~(size_t)255));

  hipLaunchKernelGGL(init_k,   dim3(1),           dim3(64),  0, stream, ws, out);
  hipLaunchKernelGGL(router_k, dim3(B_TOK),       dim3(64),  0, stream, x, rw, rb, ws, out);
  hipLaunchKernelGGL(scan_k,   dim3(1),           dim3(64),  0, stream, ws, out);
  hipLaunchKernelGGL(group_k,  dim3(E_NUM),       dim3(256), 0, stream, ws);
  hipLaunchKernelGGL(stats_k,  dim3(24),          dim3(256), 0, stream, x, ws);
  hipLaunchKernelGGL(gemm_k,   dim3(24, 32, 8),   dim3(256), 0, stream, x, We, be, bd, ws, pre);
  hipLaunchKernelGGL(var_k,    dim3(E_NUM),       dim3(256), 0, stream, ws);
  hipLaunchKernelGGL(topk_k,   dim3(B_TOK / 4),   dim3(256), 0, stream, pre, ws, out);
  hipLaunchKernelGGL(decode_k, dim3(B_TOK),       dim3(192), 0, stream, x, Wd, bd, ws, out);
  hipLaunchKernelGGL(final_k,  dim3(1),           dim3(64),  0, stream, ws, out);
}